// Round 9
// baseline (243.821 us; speedup 1.0000x reference)
//
#include <hip/hip_runtime.h>
#include <hip/hip_bf16.h>

// MoChA. Round 24: occupancy round for the mid-size kernels. (1) energy
// z-split (mono/chunk in separate blocks, 512 blocks -> 2/CU, 16 waves/CU,
// single acc); (2) mask converted once to int8 in prep_all (energy reads
// 1B/elem); (3) context 512-thread blocks (8 waves/CU) with padded LDS
// (bS[128][65], vS[128][36]) killing the 16-way vS bank conflict.
// GEMM core / alpha path / beta unchanged from R23.
// 8 dispatches. B=8, Q=128, K=1024, D=512, HM=HC=4, CHUNK=4.

#define NEG_INF (-3.402823466e38f)
#define EPS_MOCHA 1e-6f
#define INV_SCALE 0.04419417382415922f  // 1/sqrt(512)

typedef _Float16 half8 __attribute__((ext_vector_type(8)));
typedef _Float16 half4v __attribute__((ext_vector_type(4)));
typedef float f32x4 __attribute__((ext_vector_type(4)));

// Counted-vmcnt barrier (GEMM cores).
#define WAITBAR(N) asm volatile("s_waitcnt vmcnt(" #N ") lgkmcnt(0)\n\ts_barrier" ::: "memory")
// LDS-only barrier: does NOT drain vmcnt -> register prefetch loads survive.
#define BARLG() asm volatile("s_waitcnt lgkmcnt(0)\n\ts_barrier" ::: "memory")

__device__ __forceinline__ float frcp(float x) { return __builtin_amdgcn_rcpf(x); }

// ---------------------------------------------------------------------------
// Wave64 inclusive add-scan via DPP: 6 VALU-latency steps.
// ---------------------------------------------------------------------------
__device__ __forceinline__ float wave_incl_scan(float x)
{
    int v;
    v = __builtin_amdgcn_update_dpp(0, __builtin_bit_cast(int, x), 0x111, 0xF, 0xF, false);
    x += __builtin_bit_cast(float, v);   // row_shr:1
    v = __builtin_amdgcn_update_dpp(0, __builtin_bit_cast(int, x), 0x112, 0xF, 0xF, false);
    x += __builtin_bit_cast(float, v);   // row_shr:2
    v = __builtin_amdgcn_update_dpp(0, __builtin_bit_cast(int, x), 0x114, 0xF, 0xF, false);
    x += __builtin_bit_cast(float, v);   // row_shr:4
    v = __builtin_amdgcn_update_dpp(0, __builtin_bit_cast(int, x), 0x118, 0xF, 0xF, false);
    x += __builtin_bit_cast(float, v);   // row_shr:8 -> row-inclusive
    v = __builtin_amdgcn_update_dpp(0, __builtin_bit_cast(int, x), 0x142, 0xA, 0xF, false);
    x += __builtin_bit_cast(float, v);   // row_bcast:15 -> rows 1,3
    v = __builtin_amdgcn_update_dpp(0, __builtin_bit_cast(int, x), 0x143, 0xC, 0xF, false);
    x += __builtin_bit_cast(float, v);   // row_bcast:31 -> rows 2,3
    return x;
}

__device__ __forceinline__ half8 cvt8(float4 a, float4 b)
{
    half8 h = {(_Float16)a.x, (_Float16)a.y, (_Float16)a.z, (_Float16)a.w,
               (_Float16)b.x, (_Float16)b.y, (_Float16)b.z, (_Float16)b.w};
    return h;
}

// ---------------------------------------------------------------------------
// prep_all: blocks 0..383 transpose-pack 6 weights -> Wt[n][k] fp16;
// blocks 384..2687 cvt key_x++query_x fp32 -> X16 fp16;
// blocks 2688..3199 convert mask int32 -> int8 (exact 0/1).
// Grid: 3200 x 256.
// ---------------------------------------------------------------------------
__global__ __launch_bounds__(256) void prep_all(
    const float* __restrict__ wk_m, const float* __restrict__ wk_c,
    const float* __restrict__ wv, const float* __restrict__ wq_m,
    const float* __restrict__ wq_c, const float* __restrict__ wo,
    const float* __restrict__ key_x, const float* __restrict__ query_x,
    const int* __restrict__ mask,
    _Float16* __restrict__ Wt5, _Float16* __restrict__ Wt_wo,
    _Float16* __restrict__ X16, signed char* __restrict__ mask8)
{
    __shared__ float T[64][65];
    const int bid = blockIdx.x;
    const int t = threadIdx.x;
    if (bid < 384) {
        const int z = bid >> 6, w = bid & 63;
        const float* W = (z == 0) ? wk_m : (z == 1) ? wk_c : (z == 2) ? wv
                       : (z == 3) ? wq_m : (z == 4) ? wq_c : wo;
        _Float16* O = (z < 5) ? (Wt5 + (size_t)z * 262144) : Wt_wo;
        const int n0 = (w & 7) * 64, k0 = (w >> 3) * 64;
        const int rr = t >> 4, cc = (t & 15) * 4;
#pragma unroll
        for (int r = 0; r < 4; ++r) {
            int k = r * 16 + rr;
            float4 v = *(const float4*)(W + (size_t)(k0 + k) * 512 + n0 + cc);
            T[k][cc + 0] = v.x; T[k][cc + 1] = v.y;
            T[k][cc + 2] = v.z; T[k][cc + 3] = v.w;
        }
        __syncthreads();
        const int nn = t >> 2, kc = (t & 3) * 16;
        _Float16 tmp[16];
#pragma unroll
        for (int i = 0; i < 16; ++i) tmp[i] = (_Float16)T[kc + i][nn];
        _Float16* Op = O + (size_t)(n0 + nn) * 512 + k0 + kc;
        *(half8*)(Op)     = *(half8*)&tmp[0];
        *(half8*)(Op + 8) = *(half8*)&tmp[8];
    } else if (bid < 2688) {
        const size_t KELEMS = (size_t)8192 * 512;
        size_t o = ((size_t)(bid - 384) * 256 + t) * 8;
        const float* s = (o < KELEMS) ? (key_x + o) : (query_x + (o - KELEMS));
        float4 a = *(const float4*)s;
        float4 b = *(const float4*)(s + 4);
        *(half8*)(X16 + o) = cvt8(a, b);
    } else {
        size_t o = ((size_t)(bid - 2688) * 256 + t) * 8;   // 1M total elems
        const int* mp = mask + o;
        int4 a = *(const int4*)mp;
        int4 b = *(const int4*)(mp + 4);
        unsigned long long pk = 0;
        pk |= (unsigned long long)(a.x != 0) << 0;
        pk |= (unsigned long long)(a.y != 0) << 8;
        pk |= (unsigned long long)(a.z != 0) << 16;
        pk |= (unsigned long long)(a.w != 0) << 24;
        pk |= (unsigned long long)(b.x != 0) << 32;
        pk |= (unsigned long long)(b.y != 0) << 40;
        pk |= (unsigned long long)(b.z != 0) << 48;
        pk |= (unsigned long long)(b.w != 0) << 56;
        *(unsigned long long*)(mask8 + o) = pk;
    }
}

// ---------------------------------------------------------------------------
// Async global->LDS 16B copy (wave-uniform base + lane*16 layout).
// ---------------------------------------------------------------------------
__device__ __forceinline__ void stage16(const _Float16* src, _Float16* dst)
{
    __builtin_amdgcn_global_load_lds(
        (const __attribute__((address_space(1))) void*)src,
        (__attribute__((address_space(3))) void*)dst, 16, 0, 0);
}

// ---------------------------------------------------------------------------
// 8-wave GEMM core (512 threads), both operands fp16 via global_load_lds.
// 128x128 tile, BK=32; wave grid 2m x 4n, wave tile 64x32 -> acc[4][2]
// (32 VGPR). 3 LDS buffers: stage tile ks+2 at top, compute buf[ks%3],
// WAITBAR(2) drains tile ks+1 only; ks+2 crosses the barrier in flight.
// ---------------------------------------------------------------------------
template <int NSTEPS>
__device__ __forceinline__ void gemm8_f16(
    const _Float16* __restrict__ Abase, const _Float16* __restrict__ Bbase,
    _Float16* As, _Float16* Bs, f32x4 acc[4][2])
{
    const int tid = threadIdx.x;
    const int lane = tid & 63, wave = tid >> 6;
    const int wm = wave >> 2, wn = wave & 3;
    const int col = lane & 15, quad = lane >> 4;
    const int r0 = tid >> 2, seg = tid & 3;

    const _Float16* Ag = Abase + (size_t)r0 * 512 + seg * 8;
    const _Float16* Bg = Bbase + (size_t)r0 * 512 + seg * 8;

    stage16(Ag, As + tid * 8);
    stage16(Bg, Bs + tid * 8);
    if (NSTEPS > 1) {
        stage16(Ag + 32, As + 4096 + tid * 8);
        stage16(Bg + 32, Bs + 4096 + tid * 8);
        WAITBAR(2);   // tile 0 landed; tile 1 in flight
    } else {
        WAITBAR(0);
    }

#pragma unroll
    for (int ks = 0; ks < NSTEPS; ++ks) {
        const int cur = ks % 3;
        if (ks + 2 < NSTEPS) {
            const int s2 = (ks + 2) % 3;
            stage16(Ag + (ks + 2) * 32, As + s2 * 4096 + tid * 8);
            stage16(Bg + (ks + 2) * 32, Bs + s2 * 4096 + tid * 8);
        }
        const _Float16* Afr = As + cur * 4096 + (size_t)(wm * 64 + col) * 32 + quad * 8;
        const _Float16* Bfr = Bs + cur * 4096 + (size_t)(wn * 32 + col) * 32 + quad * 8;
        half8 a[4], b[2];
#pragma unroll
        for (int t = 0; t < 4; ++t) a[t] = *(const half8*)(Afr + (size_t)t * 16 * 32);
#pragma unroll
        for (int t = 0; t < 2; ++t) b[t] = *(const half8*)(Bfr + (size_t)t * 16 * 32);
#pragma unroll
        for (int mt = 0; mt < 4; ++mt)
#pragma unroll
            for (int nt = 0; nt < 2; ++nt)
                acc[mt][nt] = __builtin_amdgcn_mfma_f32_16x16x32_f16(
                    a[mt], b[nt], acc[mt][nt], 0, 0, 0);
        if (ks + 2 < NSTEPS)      WAITBAR(2);  // tile ks+1 ready; ks+2 in flight
        else if (ks + 1 < NSTEPS) WAITBAR(0);
    }
}

__device__ __forceinline__ void proj_epilogue8(
    f32x4 acc[4][2], const float* __restrict__ bias, void* __restrict__ Cv,
    int m0, int n0, int f16o)
{
    const int tid = threadIdx.x;
    const int lane = tid & 63, wave = tid >> 6;
    const int wm = wave >> 2, wn = wave & 3;
    const int col = lane & 15, quad = lane >> 4;
    float bnt[2];
#pragma unroll
    for (int nt = 0; nt < 2; ++nt)
        bnt[nt] = bias[n0 + wn * 32 + nt * 16 + col];
#pragma unroll
    for (int mt = 0; mt < 4; ++mt) {
        const int rowb = m0 + wm * 64 + mt * 16 + quad * 4;
#pragma unroll
        for (int nt = 0; nt < 2; ++nt) {
            const int cc = n0 + wn * 32 + nt * 16 + col;
#pragma unroll
            for (int r = 0; r < 4; ++r) {
                float v = acc[mt][nt][r] + bnt[nt];
                if (f16o)
                    ((_Float16*)Cv)[(size_t)(rowb + r) * 512 + cc] = (_Float16)v;
                else
                    ((float*)Cv)[(size_t)(rowb + r) * 512 + cc] = v;
            }
        }
    }
}

// ---------------------------------------------------------------------------
// Merged key+query projection, A = X16 fp16 (key rows 0..8191, query rows
// 8192..9215). Flattened 832-block grid, bijective XCD swizzle (832=8*104).
// All outputs fp16 (incl. V16).
// ---------------------------------------------------------------------------
__global__ __launch_bounds__(512, 8) void mfma_proj5(
    const _Float16* __restrict__ X16, const _Float16* __restrict__ Wt5,
    const float* __restrict__ b0, void* __restrict__ C0,
    const float* __restrict__ b1, void* __restrict__ C1,
    const float* __restrict__ b2, void* __restrict__ C2,
    const float* __restrict__ b3, void* __restrict__ C3,
    const float* __restrict__ b4, void* __restrict__ C4)
{
    __shared__ _Float16 As[12288];
    __shared__ _Float16 Bs[12288];
    const int bid = (blockIdx.x & 7) * 104 + (blockIdx.x >> 3);
    int g, mblk, nblk;
    if (bid < 768) {
        g = bid >> 8; mblk = (bid & 255) >> 2; nblk = bid & 3;
    } else {
        const int t = bid - 768;
        g = 3 + (t >> 5); mblk = (t & 31) >> 2; nblk = t & 3;
    }
    const bool qry = g >= 3;
    const _Float16* A = X16 + (qry ? (size_t)8192 * 512 : 0);
    const _Float16* Wt = Wt5 + (size_t)g * 262144;
    const float* bias = (g == 0) ? b0 : (g == 1) ? b1 : (g == 2) ? b2
                      : (g == 3) ? b3 : b4;
    void* Cv = (g == 0) ? C0 : (g == 1) ? C1 : (g == 2) ? C2
             : (g == 3) ? C3 : C4;
    const int m0 = mblk * 128, n0 = nblk * 128;

    f32x4 acc[4][2];
#pragma unroll
    for (int mt = 0; mt < 4; ++mt)
#pragma unroll
        for (int nt = 0; nt < 2; ++nt) acc[mt][nt] = (f32x4)0.f;
    gemm8_f16<16>(A + (size_t)m0 * 512, Wt + (size_t)n0 * 512, As, Bs, acc);
    proj_epilogue8(acc, bias, Cv, m0, n0, 1);
}

// ---------------------------------------------------------------------------
// Output projection (A = cv16 fp16, M=1024, fp32 out). Grid: (8, 4).
// ---------------------------------------------------------------------------
__global__ __launch_bounds__(512, 4) void mfma_proj_out(
    const _Float16* __restrict__ A16, const _Float16* __restrict__ Wt,
    const float* __restrict__ bias, float* __restrict__ C)
{
    __shared__ _Float16 As[12288];
    __shared__ _Float16 Bs[12288];
    const int m0 = blockIdx.x * 128, n0 = blockIdx.y * 128;
    f32x4 acc[4][2];
#pragma unroll
    for (int mt = 0; mt < 4; ++mt)
#pragma unroll
        for (int nt = 0; nt < 2; ++nt) acc[mt][nt] = (f32x4)0.f;
    gemm8_f16<16>(A16 + (size_t)m0 * 512, Wt + (size_t)n0 * 512, As, Bs, acc);
    proj_epilogue8(acc, bias, C, m0, n0, 0);
}

// ---------------------------------------------------------------------------
// Energy (z-split): z<8 mono (b=z, +r, fp32 e_mono); z>=8 chunk (fp16
// e_chunk16). 512 blocks of 512 threads -> 2 blocks/CU, 16 waves/CU.
// Single acc[4][2] per block; mask read as int8. Grid: (kt=8, h=4, z=16).
// ---------------------------------------------------------------------------
__global__ __launch_bounds__(512, 4) void energy_mfma(
    const _Float16* __restrict__ Qm, const _Float16* __restrict__ Km,
    const _Float16* __restrict__ Qc, const _Float16* __restrict__ Kc,
    const signed char* __restrict__ mask8, float* __restrict__ e_mono,
    _Float16* __restrict__ e_chunk16, const float* __restrict__ r_ptr)
{
    __shared__ _Float16 As[12288];
    __shared__ _Float16 Bs[12288];
    const int tid = threadIdx.x;
    const int lane = tid & 63, wave = tid >> 6;
    const int wm = wave >> 2, wn = wave & 3;
    const int col = lane & 15, quad = lane >> 4;
    const int kt0 = blockIdx.x * 128;
    const int h = blockIdx.y;
    const int z = blockIdx.z;
    const int b = z & 7;
    const bool mono = z < 8;
    const _Float16* Qp = mono ? Qm : Qc;
    const _Float16* Kp = mono ? Km : Kc;
    const float rv = mono ? r_ptr[0] : 0.f;

    f32x4 acc[4][2];
#pragma unroll
    for (int mt = 0; mt < 4; ++mt)
#pragma unroll
        for (int nt = 0; nt < 2; ++nt) acc[mt][nt] = (f32x4)0.f;
    gemm8_f16<4>(Qp + (size_t)(b * 128) * 512 + h * 128,
                 Kp + (size_t)(b * 1024 + kt0) * 512 + h * 128, As, Bs, acc);

#pragma unroll
    for (int mt = 0; mt < 4; ++mt) {
        const int qb = wm * 64 + mt * 16 + quad * 4;
#pragma unroll
        for (int nt = 0; nt < 2; ++nt) {
            const int kc = kt0 + wn * 32 + nt * 16 + col;
#pragma unroll
            for (int r = 0; r < 4; ++r) {
                const int q = qb + r;
                const int mv = mask8[((size_t)b * 128 + q) * 1024 + kc];
                const size_t oi = (((size_t)b * 4 + h) * 128 + q) * 1024 + kc;
                float v = acc[mt][nt][r] * INV_SCALE + rv;
                if (mono) e_mono[oi] = mv ? v : NEG_INF;
                else      e_chunk16[oi] = (_Float16)(mv ? v : NEG_INF);
            }
        }
    }
}

// ---------------------------------------------------------------------------
// transcend_row: (pcp, invcp) for one (b,h,q) row computed by one wave.
// Fast transcendentals (__expf/__logf/v_rcp).
// ---------------------------------------------------------------------------
__device__ __forceinline__ void transcend_row(
    const float* __restrict__ Erow, int lane, float o_pcp[16], float o_inv[16])
{
    const float* E = Erow + lane * 16;
    float e[16];
    *(float4*)&e[0]  = *(const float4*)(E);
    *(float4*)&e[4]  = *(const float4*)(E + 4);
    *(float4*)&e[8]  = *(const float4*)(E + 8);
    *(float4*)&e[12] = *(const float4*)(E + 12);

    float p[16], l[16];
#pragma unroll
    for (int i = 0; i < 16; ++i) {
        p[i] = frcp(1.f + __expf(-e[i]));
        l[i] = __logf(fmaxf(1.f - p[i], EPS_MOCHA));
    }
    float incl[16];
    incl[0] = l[0];
#pragma unroll
    for (int i = 1; i < 16; ++i) incl[i] = incl[i - 1] + l[i];
    float total = incl[15];
    float x = wave_incl_scan(total);
    float base = x - total;  // exclusive across lanes
#pragma unroll
    for (int i = 0; i < 16; ++i) {
        float cl = base + (i ? incl[i - 1] : 0.f);
        float cp = __expf(cl);
        o_pcp[i] = p[i] * cp;
        o_inv[i] = frcp(fmaxf(cp, EPS_MOCHA));
    }
}

// ---------------------------------------------------------------------------
// alpha_pre: block = 8 consecutive rows (one wave each, same (b,h) panel);
// pcp shared wave->wave via LDS. Only wave 0 recomputes the previous row.
// G_q = pcp_{q-1} * invcp_q. Grid: 512 x 512.
// ---------------------------------------------------------------------------
#define SW2(k) ((k) + ((k) >> 4))

__global__ __launch_bounds__(512) void alpha_pre(
    const float* __restrict__ e_mono, float* __restrict__ G,
    float* __restrict__ pcp)
{
    __shared__ float pshare[8][1088];
    const int tid = threadIdx.x;
    const int lane = tid & 63;
    const int wid = tid >> 6;
    const int row = blockIdx.x * 8 + wid;
    const int q = row & 127;

    float pq[16], iq[16];
    transcend_row(e_mono + (size_t)row * 1024, lane, pq, iq);

    float* P = pcp + (size_t)row * 1024 + lane * 16;
    *(float4*)(P)      = *(float4*)&pq[0];
    *(float4*)(P + 4)  = *(float4*)&pq[4];
    *(float4*)(P + 8)  = *(float4*)&pq[8];
    *(float4*)(P + 12) = *(float4*)&pq[12];

#pragma unroll
    for (int i = 0; i < 16; ++i)
        pshare[wid][SW2(lane * 16 + i)] = pq[i];
    __syncthreads();

    float g[16];
    if (q == 0) {  // only wid==0 on panel boundary
#pragma unroll
        for (int i = 0; i < 16; ++i) g[i] = 0.f;
        if (lane == 0) g[0] = iq[0];
    } else if (wid > 0) {
#pragma unroll
        for (int i = 0; i < 16; ++i)
            g[i] = pshare[wid - 1][SW2(lane * 16 + i)] * iq[i];
    } else {
        float pm[16], im[16];
        transcend_row(e_mono + (size_t)(row - 1) * 1024, lane, pm, im);
#pragma unroll
        for (int i = 0; i < 16; ++i) g[i] = pm[i] * iq[i];
    }
    float* Gp = G + (size_t)row * 1024 + lane * 16;
    *(float4*)(Gp)      = *(float4*)&g[0];
    *(float4*)(Gp + 4)  = *(float4*)&g[4];
    *(float4*)(Gp + 8)  = *(float4*)&g[8];
    *(float4*)(Gp + 12) = *(float4*)&g[12];
}

// ---------------------------------------------------------------------------
// alpha_scan: one 256-thread block per (b,h); 4 k/lane; named prefetch
// registers g0..g3, q-loop unrolled by 4 (no scratch). Streams G only,
// writes S. Double-buffered cross-wave carry + one lgkmcnt-only barrier.
// ---------------------------------------------------------------------------
__global__ __launch_bounds__(256) void alpha_scan(
    const float* __restrict__ G, float* __restrict__ S)
{
    __shared__ float carry[2][4];
    const int tid = threadIdx.x;
    const int lane = tid & 63, wid = tid >> 6;
    const int bh = blockIdx.x;
    const float* Gp = G + (size_t)bh * 131072 + tid * 4;
    float* Sp = S + (size_t)bh * 131072 + tid * 4;

    float4 g0 = *(const float4*)(Gp);
    float4 g1 = *(const float4*)(Gp + 1024);
    float4 g2 = *(const float4*)(Gp + 2048);
    float4 g3 = *(const float4*)(Gp + 3072);

    float Sv0 = 1.f, Sv1 = 1.f, Sv2 = 1.f, Sv3 = 1.f;  // S_{-1} = ones

#define SCAN_STEP(GV, QQ)                                                    \
    {                                                                        \
        float i0 = GV.x * Sv0;                                               \
        float i1 = fmaf(GV.y, Sv1, i0);                                      \
        float i2 = fmaf(GV.z, Sv2, i1);                                      \
        float i3 = fmaf(GV.w, Sv3, i2);                                      \
        float x = wave_incl_scan(i3);                                        \
        float base = x - i3;                                                 \
        if (lane == 63) carry[(QQ) & 1][wid] = x;                            \
        BARLG();                                                             \
        float pre = 0.f;                                                     \
        if (wid > 0) pre += carry[(QQ) & 1][0];                              \
        if (wid > 1) pre += carry[(QQ) & 1][1];                              \
        if (wid > 2) pre += carry[(QQ) & 1][2];                              \
        float ba = pre + base;                                               \
        Sv0 = ba + i0; Sv1 = ba + i1; Sv2 = ba + i2; Sv3 = ba + i3;          \
        float4 sv = {Sv0, Sv1, Sv2, Sv3};                                    \
        *(float4*)(Sp + (size_t)(QQ) * 1024) = sv;                           \
    }

    for (int q = 0; q < 128; q += 4) {
        SCAN_STEP(g0, q);
        if (q + 4 < 128) g0 = *(const float4*)(Gp + (size_t)(q + 4) * 1024);
        SCAN_STEP(g1, q + 1);
        if (q + 5 < 128) g1 = *(const float4*)(Gp + (size_t)(q + 5) * 1024);
        SCAN_STEP(g2, q + 2);
        if (q + 6 < 128) g2 = *(const float4*)(Gp + (size_t)(q + 6) * 1024);
        SCAN_STEP(g3, q + 3);
        if (q + 7 < 128) g3 = *(const float4*)(Gp + (size_t)(q + 7) * 1024);
    }
#undef SCAN_STEP
}

// ---------------------------------------------------------------------------
// Beta: alpha = pcp*S reconstructed on load; moving sums via shfl; fast
// exp/rcp. Grid: (q=128, b=8).
// ---------------------------------------------------------------------------
__global__ __launch_bounds__(256) void beta_kernel(
    const _Float16* __restrict__ e_chunk16, const float* __restrict__ pcp,
    const float* __restrict__ S, _Float16* __restrict__ beta)
{
    __shared__ float red[4];
    __shared__ float edge_sx[4][4];    // lane63's sx per wave
    __shared__ float edge_t[4][4][4];  // lane0's t per wave per hm
    const int q = blockIdx.x, b = blockIdx.y;
    const int tid = threadIdx.x;
    const int lane = tid & 63, wid = tid >> 6;
    const int k4 = tid * 4;

    float av[4][4];
#pragma unroll
    for (int hm = 0; hm < 4; ++hm) {
        const size_t off = (((size_t)b * 4 + hm) * 128 + q) * 1024 + k4;
        float4 pv = *(const float4*)(pcp + off);
        float4 sv = *(const float4*)(S + off);
        av[hm][0] = pv.x * sv.x;
        av[hm][1] = pv.y * sv.y;
        av[hm][2] = pv.z * sv.z;
        av[hm][3] = pv.w * sv.w;
    }

    for (int hc = 0; hc < 4; ++hc) {
        half4v ev = *(const half4v*)(e_chunk16 + (((size_t)b * 4 + hc) * 128 + q) * 1024 + k4);
        float e[4] = {(float)ev[0], (float)ev[1], (float)ev[2], (float)ev[3]};

        float mx = fmaxf(fmaxf(e[0], e[1]), fmaxf(e[2], e[3]));
#pragma unroll
        for (int off = 32; off >= 1; off >>= 1)
            mx = fmaxf(mx, __shfl_xor(mx, off, 64));
        if (lane == 0) red[wid] = mx;
        __syncthreads();  // bar1: red ready (also fences edge reuse)
        mx = fmaxf(fmaxf(red[0], red[1]), fmaxf(red[2], red[3]));

        float sx[4];
#pragma unroll
        for (int i = 0; i < 4; ++i)
            sx[i] = fmaxf(__expf(e[i] - mx), 1e-5f);
        if (lane == 63) {
            edge_sx[wid][0] = sx[0]; edge_sx[wid][1] = sx[1];
            edge_sx[wid][2] = sx[2]; edge_sx[wid][3] = sx[3];
        }
        __syncthreads();  // bar2: edge_sx ready

        float p1 = __shfl_up(sx[3], 1, 64);
        float p2 = __shfl_up(sx[2], 1, 64);
        float p3 = __shfl_up(sx[1], 1, 64);
        if (lane == 0) {
            if (wid > 0) {
                p1 = edge_sx[wid - 1][3];
                p2 = edge_sx[wid - 1][2];
                p3 = edge_sx[wid - 1][1];
            } else {
                p1 = 0.f; p2 = 0.f; p3 = 0.f;
            }
        }
        float den[4];
        den[0] = sx[0] + p1 + p2 + p3;
        den[1] = sx[1] + sx[0] + p1 + p2;
        den[2] = sx[2] + sx[1] + sx[0] + p1;
        den[3] = sx[3] + sx[2] + sx[1] + sx[0];
        float rd[4];
#pragma unroll
        for (int i = 0; i < 4; ++i) rd[i] = frcp(den[i]);

        float t[4][4];
#pragma unroll
        for (int hm = 0; hm < 4; ++hm)
#pragma unroll
            for (int i = 0; i < 4; ++i)
                t[hm][i] = av[hm][i] * rd[i];
        if (lane == 0) {
#pragma unroll
            for (int hm = 0; hm < 4; ++hm) {
                edge_t[wid][hm][0] = t[hm][0]; edge_t[wid][hm][1] = t[hm][1];
                edge_t[wid][hm][2] = t[hm][2]; edge_t[wid][hm][3] = t[hm][3];
            }
        }
        __syncthreads();  // bar3: edge_t ready

#pragma unroll
        for (int hm = 0; hm < 4; ++hm) {
            float n1 = __shfl_down(t[hm][0], 1, 64);
            float n2 = __shfl_down(t[hm][1], 1, 64);
            float n3 = __shfl_down(t[hm][2], 1, 64);
            if (lane == 63) {
                if (wid < 3) {
                    n1 = edge_t[wid + 1][hm][0];
                    n2 = edge_t[wid + 1][hm][1];
                    n3 = edge_t[wid + 1][hm][2];
                } else {
                    n1 = 0.f; n2 = 0.f; n3 = 0.f;
                }
            }
            float o0 = sx[0] * (t[hm][0] + t[hm][1] + t[hm][2] + t[hm][3]);
            float o1 = sx[1] * (t[hm][1] + t[hm][2] + t[hm][3] + n1);
            float o2 = sx[2] * (t[hm][2] + t[hm][3] + n1 + n2);
            float o3 = sx[3] * (t[hm][3] + n1 + n2 + n3);
            _Float16* Brow = beta + (((size_t)b * 16 + hm * 4 + hc) * 128 + q) * 1024;
            half4v hv = {(_Float16)o0, (_Float16)o1, (_Float16)o2, (_Float16)o3};
            *(half4v*)(Brow + k4) = hv;
        }
    }
}

// ---------------------------------------------------------------------------
// Context: 512-thread blocks (8 waves/CU), 128-k chunks, padded LDS
// (bS[128][65], vS[128][36] -> 16B-aligned float4, ~2-way conflicts max).
// cv16[b,q,h*32+d] = sum_k beta16[b,h,q,k] * V16[b,k,h*32+d]
// Grid: (2, 16, 8).
// ---------------------------------------------------------------------------
__global__ __launch_bounds__(512) void context_kernel(
    const _Float16* __restrict__ beta, const _Float16* __restrict__ V16,
    _Float16* __restrict__ cv16)
{
    __shared__ float bS[128][65];
    __shared__ float vS[128][36];
    const int qh = blockIdx.x, h = blockIdx.y, b = blockIdx.z;
    const int tid = threadIdx.x;
    const int ty = tid >> 3;           // 0..63 (q row)
    const int tx = tid & 7;            // 0..7  (d group of 4)
    const int q0 = qh * 64;

    const _Float16* Bbase = beta + (((size_t)b * 16 + h) * 128 + q0) * 1024;
    const _Float16* Vbase = V16 + (size_t)b * 1024 * 512 + h * 32;

    float acc[4] = {0.f, 0.f, 0.f, 0.f};

    for (int k0 = 0; k0 < 1024; k0 += 128) {
        {   // stage beta: 64 q x 128 k; 16 elems/thread (2x half8)
            const int r = tid >> 3, c = tid & 7;
            half8 v0 = *(const half8*)(Bbase + (size_t)r * 1024 + k0 + c * 16);
            half8 v1 = *(const half8*)(Bbase + (size_t)r * 1024 + k0 + c * 16 + 8);
#pragma unroll
            for (int j = 0; j < 8; ++j) {
                bS[c * 16 + j][r]     = (float)v0[j];
                bS[c * 16 + 8 + j][r] = (float)v1[j];
            }
        }
        {   // stage V: 128 k x 32 d; 8 elems/thread (2x half4v)
            const int kk = tid >> 2, cc = tid & 3;
            half4v w0 = *(const half4v*)(Vbase + (size_t)(k0 + kk) * 512 + cc * 8);
            half4v w1 = *(const half4v*)(Vbase + (size_t)(k0 + kk) * 512 + cc * 8 + 4);
#pragma unroll
            for (int j = 0; j < 4; ++j) {
                vS[kk][cc * 8 + j]     = (float)w0[j];
                vS[kk][cc * 8 + 4 + j] = (float)w1[j];
            }
        }
        __syncthreads();
#pragma unroll 8
        for (int kk = 0; kk < 128; ++kk) {
            float a = bS[kk][ty];
            float bb[4];
            *(float4*)bb = *(const float4*)&vS[kk][tx * 4];
#pragma unroll
            for (int j = 0; j < 4; ++j) acc[j] = fmaf(a, bb[j], acc[j]);
        }
        __syncthreads();
    }
    _Float16* Cp = cv16 + ((size_t)b * 128 + q0 + ty) * 512 + h * 32 + tx * 4;
    half4v hv = {(_Float16)acc[0], (_Float16)acc[1],
                 (_Float16)acc[2], (_Float16)acc[3]};
    *(half4v*)Cp = hv;
}

// ---------------------------------------------------------------------------
extern "C" void kernel_launch(void* const* d_in, const int* in_sizes, int n_in,
                              void* d_out, int out_size, void* d_ws, size_t ws_size,
                              hipStream_t stream)
{
    const float* key_x   = (const float*)d_in[0];
    const float* query_x = (const float*)d_in[1];
    const int*   mask    = (const int*)d_in[2];
    const float* wk_m = (const float*)d_in[3];
    const float* bk_m = (const float*)d_in[4];
    const float* wq_m = (const float*)d_in[5];
    const float* bq_m = (const float*)d_in[6];
    const float* r    = (const float*)d_in[7];
    const float* wk_c = (const float*)d_in[8];
    const float* bk_c = (const float*)d_in[9];
    const float* wq_c = (const float*)d_in[10];
    const float* bq_c = (const float*)d_in[11];
    const float* wv   = (const float*)d_in[12];
    const float* bv   = (const float*)d_in[13];
    const float* wo   = (const float*)d_in[14];
    const float* bo   = (const float*)d_in[15];
    float* out = (float*)d_out;

    float* ws = (float*)d_ws;
    _Float16* hws = (_Float16*)d_ws;
    const size_t MEGF = 1024 * 1024;
    // Float-unit layout (fp16 offsets are 2x float offsets), lifetime-audited:
    //  phase A (prep_all, proj5, energy):
    //    Km16 f[0,2), Kc16 f[2,4), Qm16 f[4,4.25), Qc16 f[4.25,4.5),
    //    X16 f[8,10.25) [dead after proj5], mask8 f[10.25,10.5),
    //    e_mono f[11,15), e_chunk16 f[17,19), V16 f[19,21),
    //    Wt5 f[27,27.625), Wt_wo f[27.625,27.75) [live to proj_out]
    //  phase B (alpha): G f[0,4), pcp f[4,8), S f[23,27)
    //  phase C (beta/context): beta16 f[8,16) (X16+mask8+e_mono dead;
    //    pcp/S live), cv16 f[27.75,28). Peak 28 MEGF.
    _Float16* Km16  = hws;                          // f 0
    _Float16* Kc16  = hws + 4 * MEGF;               // f 2
    _Float16* Qm16  = hws + 8 * MEGF;               // f 4
    _Float16* Qc16  = hws + 8 * MEGF + 524288;      // f 4.25
    _Float16* X16   = hws + 16 * MEGF;              // f 8, 2.25 MEGF
    signed char* mask8 = (signed char*)(hws + 20 * MEGF + MEGF / 2);  // f 10.25
    float* e_mono  = ws + 11 * MEGF;
    _Float16* e_chunk16 = hws + 34 * MEGF;          // f 17
    _Float16* V16  = hws + 38 * MEGF;               // f 19, 2 MEGF
    float* G       = ws;                            // f 0
    float* pcp     = ws + 4 * MEGF;                 // f 4
    float* S       = ws + 23 * MEGF;                // f 23
    _Float16* beta16 = hws + 16 * MEGF;             // f 8 (phase C)
    _Float16* Wt5   = hws + 54 * MEGF;              // f 27
    _Float16* Wt_wo = hws + 54 * MEGF + 5 * 262144; // f 27.625
    _Float16* cv16  = hws + 55 * MEGF + MEGF / 2;   // f 27.75

    // 0) weight packing + activation cvt + mask->int8 in one launch
    prep_all<<<dim3(3200), 256, 0, stream>>>(
        wk_m, wk_c, wv, wq_m, wq_c, wo, key_x, query_x, mask,
        Wt5, Wt_wo, X16, mask8);
    // 1) all five projections (832-block grid, 512 threads, XCD swizzle)
    mfma_proj5<<<dim3(832), 512, 0, stream>>>(
        X16, Wt5, bk_m, Km16, bk_c, Kc16, bv, V16, bq_m, Qm16, bq_c, Qc16);
    // 2) both energies, z-split (512 blocks -> 2/CU, 16 waves/CU)
    energy_mfma<<<dim3(8, 4, 16), 512, 0, stream>>>(
        Qm16, Km16, Qc16, Kc16, mask8, e_mono, e_chunk16, r);
    // 3) monotonic alpha: G/pcp precompute + k-parallel scan (G-only stream)
    alpha_pre<<<dim3(512), 512, 0, stream>>>(e_mono, G, pcp);
    alpha_scan<<<dim3(32), 256, 0, stream>>>(G, S);
    // 4) chunkwise beta (pcp*S on load)
    beta_kernel<<<dim3(128, 8), 256, 0, stream>>>(e_chunk16, pcp, S, beta16);
    // 5) context vectors -> cv16 (512-thread blocks, padded LDS)
    context_kernel<<<dim3(2, 16, 8), 512, 0, stream>>>(beta16, V16, cv16);
    // 6) output projection
    mfma_proj_out<<<dim3(8, 4), 512, 0, stream>>>(cv16, Wt_wo, bo, out);
}

// Round 10
// 215.205 us; speedup vs baseline: 1.1330x; 1.1330x over previous
//
#include <hip/hip_runtime.h>
#include <hip/hip_bf16.h>

// MoChA. Round 25: (1) context_kernel rewritten as MFMA GEMM (per (b,h):
// 128q x 32d x 1024k). Old version was LDS-throughput-bound (~2048 scalar
// LDS reads/thread). New: reg-staged PADDED LDS (stride 72 halfs), double
// buffer, ONE lgkmcnt-only barrier per K-step (global loads stay in flight),
// wave tile 32x16, acc[2][1]. (2) alpha_scan writes alpha = pcp*S directly
// (pcp prefetched 4-deep in named regs, off critical path); beta reads one
// 16MB array instead of two. Everything else = R24.
// 8 dispatches. B=8, Q=128, K=1024, D=512, HM=HC=4, CHUNK=4.

#define NEG_INF (-3.402823466e38f)
#define EPS_MOCHA 1e-6f
#define INV_SCALE 0.04419417382415922f  // 1/sqrt(512)

typedef _Float16 half8 __attribute__((ext_vector_type(8)));
typedef _Float16 half4v __attribute__((ext_vector_type(4)));
typedef float f32x4 __attribute__((ext_vector_type(4)));

// Counted-vmcnt barrier (GEMM cores).
#define WAITBAR(N) asm volatile("s_waitcnt vmcnt(" #N ") lgkmcnt(0)\n\ts_barrier" ::: "memory")
// LDS-only barrier: does NOT drain vmcnt -> register prefetch loads survive.
#define BARLG() asm volatile("s_waitcnt lgkmcnt(0)\n\ts_barrier" ::: "memory")

__device__ __forceinline__ float frcp(float x) { return __builtin_amdgcn_rcpf(x); }

// ---------------------------------------------------------------------------
// Wave64 inclusive add-scan via DPP: 6 VALU-latency steps.
// ---------------------------------------------------------------------------
__device__ __forceinline__ float wave_incl_scan(float x)
{
    int v;
    v = __builtin_amdgcn_update_dpp(0, __builtin_bit_cast(int, x), 0x111, 0xF, 0xF, false);
    x += __builtin_bit_cast(float, v);   // row_shr:1
    v = __builtin_amdgcn_update_dpp(0, __builtin_bit_cast(int, x), 0x112, 0xF, 0xF, false);
    x += __builtin_bit_cast(float, v);   // row_shr:2
    v = __builtin_amdgcn_update_dpp(0, __builtin_bit_cast(int, x), 0x114, 0xF, 0xF, false);
    x += __builtin_bit_cast(float, v);   // row_shr:4
    v = __builtin_amdgcn_update_dpp(0, __builtin_bit_cast(int, x), 0x118, 0xF, 0xF, false);
    x += __builtin_bit_cast(float, v);   // row_shr:8 -> row-inclusive
    v = __builtin_amdgcn_update_dpp(0, __builtin_bit_cast(int, x), 0x142, 0xA, 0xF, false);
    x += __builtin_bit_cast(float, v);   // row_bcast:15 -> rows 1,3
    v = __builtin_amdgcn_update_dpp(0, __builtin_bit_cast(int, x), 0x143, 0xC, 0xF, false);
    x += __builtin_bit_cast(float, v);   // row_bcast:31 -> rows 2,3
    return x;
}

__device__ __forceinline__ half8 cvt8(float4 a, float4 b)
{
    half8 h = {(_Float16)a.x, (_Float16)a.y, (_Float16)a.z, (_Float16)a.w,
               (_Float16)b.x, (_Float16)b.y, (_Float16)b.z, (_Float16)b.w};
    return h;
}

// ---------------------------------------------------------------------------
// prep_all: blocks 0..383 transpose-pack 6 weights -> Wt[n][k] fp16;
// blocks 384..2687 cvt key_x++query_x fp32 -> X16 fp16;
// blocks 2688..3199 convert mask int32 -> int8 (exact 0/1).
// Grid: 3200 x 256.
// ---------------------------------------------------------------------------
__global__ __launch_bounds__(256) void prep_all(
    const float* __restrict__ wk_m, const float* __restrict__ wk_c,
    const float* __restrict__ wv, const float* __restrict__ wq_m,
    const float* __restrict__ wq_c, const float* __restrict__ wo,
    const float* __restrict__ key_x, const float* __restrict__ query_x,
    const int* __restrict__ mask,
    _Float16* __restrict__ Wt5, _Float16* __restrict__ Wt_wo,
    _Float16* __restrict__ X16, signed char* __restrict__ mask8)
{
    __shared__ float T[64][65];
    const int bid = blockIdx.x;
    const int t = threadIdx.x;
    if (bid < 384) {
        const int z = bid >> 6, w = bid & 63;
        const float* W = (z == 0) ? wk_m : (z == 1) ? wk_c : (z == 2) ? wv
                       : (z == 3) ? wq_m : (z == 4) ? wq_c : wo;
        _Float16* O = (z < 5) ? (Wt5 + (size_t)z * 262144) : Wt_wo;
        const int n0 = (w & 7) * 64, k0 = (w >> 3) * 64;
        const int rr = t >> 4, cc = (t & 15) * 4;
#pragma unroll
        for (int r = 0; r < 4; ++r) {
            int k = r * 16 + rr;
            float4 v = *(const float4*)(W + (size_t)(k0 + k) * 512 + n0 + cc);
            T[k][cc + 0] = v.x; T[k][cc + 1] = v.y;
            T[k][cc + 2] = v.z; T[k][cc + 3] = v.w;
        }
        __syncthreads();
        const int nn = t >> 2, kc = (t & 3) * 16;
        _Float16 tmp[16];
#pragma unroll
        for (int i = 0; i < 16; ++i) tmp[i] = (_Float16)T[kc + i][nn];
        _Float16* Op = O + (size_t)(n0 + nn) * 512 + k0 + kc;
        *(half8*)(Op)     = *(half8*)&tmp[0];
        *(half8*)(Op + 8) = *(half8*)&tmp[8];
    } else if (bid < 2688) {
        const size_t KELEMS = (size_t)8192 * 512;
        size_t o = ((size_t)(bid - 384) * 256 + t) * 8;
        const float* s = (o < KELEMS) ? (key_x + o) : (query_x + (o - KELEMS));
        float4 a = *(const float4*)s;
        float4 b = *(const float4*)(s + 4);
        *(half8*)(X16 + o) = cvt8(a, b);
    } else {
        size_t o = ((size_t)(bid - 2688) * 256 + t) * 8;   // 1M total elems
        const int* mp = mask + o;
        int4 a = *(const int4*)mp;
        int4 b = *(const int4*)(mp + 4);
        unsigned long long pk = 0;
        pk |= (unsigned long long)(a.x != 0) << 0;
        pk |= (unsigned long long)(a.y != 0) << 8;
        pk |= (unsigned long long)(a.z != 0) << 16;
        pk |= (unsigned long long)(a.w != 0) << 24;
        pk |= (unsigned long long)(b.x != 0) << 32;
        pk |= (unsigned long long)(b.y != 0) << 40;
        pk |= (unsigned long long)(b.z != 0) << 48;
        pk |= (unsigned long long)(b.w != 0) << 56;
        *(unsigned long long*)(mask8 + o) = pk;
    }
}

// ---------------------------------------------------------------------------
// Async global->LDS 16B copy (wave-uniform base + lane*16 layout).
// ---------------------------------------------------------------------------
__device__ __forceinline__ void stage16(const _Float16* src, _Float16* dst)
{
    __builtin_amdgcn_global_load_lds(
        (const __attribute__((address_space(1))) void*)src,
        (__attribute__((address_space(3))) void*)dst, 16, 0, 0);
}

// ---------------------------------------------------------------------------
// 8-wave GEMM core (512 threads), both operands fp16 via global_load_lds.
// 128x128 tile, BK=32; wave grid 2m x 4n, wave tile 64x32 -> acc[4][2]
// (32 VGPR). 3 LDS buffers: stage tile ks+2 at top, compute buf[ks%3],
// WAITBAR(2) drains tile ks+1 only; ks+2 crosses the barrier in flight.
// ---------------------------------------------------------------------------
template <int NSTEPS>
__device__ __forceinline__ void gemm8_f16(
    const _Float16* __restrict__ Abase, const _Float16* __restrict__ Bbase,
    _Float16* As, _Float16* Bs, f32x4 acc[4][2])
{
    const int tid = threadIdx.x;
    const int lane = tid & 63, wave = tid >> 6;
    const int wm = wave >> 2, wn = wave & 3;
    const int col = lane & 15, quad = lane >> 4;
    const int r0 = tid >> 2, seg = tid & 3;

    const _Float16* Ag = Abase + (size_t)r0 * 512 + seg * 8;
    const _Float16* Bg = Bbase + (size_t)r0 * 512 + seg * 8;

    stage16(Ag, As + tid * 8);
    stage16(Bg, Bs + tid * 8);
    if (NSTEPS > 1) {
        stage16(Ag + 32, As + 4096 + tid * 8);
        stage16(Bg + 32, Bs + 4096 + tid * 8);
        WAITBAR(2);   // tile 0 landed; tile 1 in flight
    } else {
        WAITBAR(0);
    }

#pragma unroll
    for (int ks = 0; ks < NSTEPS; ++ks) {
        const int cur = ks % 3;
        if (ks + 2 < NSTEPS) {
            const int s2 = (ks + 2) % 3;
            stage16(Ag + (ks + 2) * 32, As + s2 * 4096 + tid * 8);
            stage16(Bg + (ks + 2) * 32, Bs + s2 * 4096 + tid * 8);
        }
        const _Float16* Afr = As + cur * 4096 + (size_t)(wm * 64 + col) * 32 + quad * 8;
        const _Float16* Bfr = Bs + cur * 4096 + (size_t)(wn * 32 + col) * 32 + quad * 8;
        half8 a[4], b[2];
#pragma unroll
        for (int t = 0; t < 4; ++t) a[t] = *(const half8*)(Afr + (size_t)t * 16 * 32);
#pragma unroll
        for (int t = 0; t < 2; ++t) b[t] = *(const half8*)(Bfr + (size_t)t * 16 * 32);
#pragma unroll
        for (int mt = 0; mt < 4; ++mt)
#pragma unroll
            for (int nt = 0; nt < 2; ++nt)
                acc[mt][nt] = __builtin_amdgcn_mfma_f32_16x16x32_f16(
                    a[mt], b[nt], acc[mt][nt], 0, 0, 0);
        if (ks + 2 < NSTEPS)      WAITBAR(2);  // tile ks+1 ready; ks+2 in flight
        else if (ks + 1 < NSTEPS) WAITBAR(0);
    }
}

__device__ __forceinline__ void proj_epilogue8(
    f32x4 acc[4][2], const float* __restrict__ bias, void* __restrict__ Cv,
    int m0, int n0, int f16o)
{
    const int tid = threadIdx.x;
    const int lane = tid & 63, wave = tid >> 6;
    const int wm = wave >> 2, wn = wave & 3;
    const int col = lane & 15, quad = lane >> 4;
    float bnt[2];
#pragma unroll
    for (int nt = 0; nt < 2; ++nt)
        bnt[nt] = bias[n0 + wn * 32 + nt * 16 + col];
#pragma unroll
    for (int mt = 0; mt < 4; ++mt) {
        const int rowb = m0 + wm * 64 + mt * 16 + quad * 4;
#pragma unroll
        for (int nt = 0; nt < 2; ++nt) {
            const int cc = n0 + wn * 32 + nt * 16 + col;
#pragma unroll
            for (int r = 0; r < 4; ++r) {
                float v = acc[mt][nt][r] + bnt[nt];
                if (f16o)
                    ((_Float16*)Cv)[(size_t)(rowb + r) * 512 + cc] = (_Float16)v;
                else
                    ((float*)Cv)[(size_t)(rowb + r) * 512 + cc] = v;
            }
        }
    }
}

// ---------------------------------------------------------------------------
// Merged key+query projection, A = X16 fp16 (key rows 0..8191, query rows
// 8192..9215). Flattened 832-block grid, bijective XCD swizzle (832=8*104).
// All outputs fp16 (incl. V16).
// ---------------------------------------------------------------------------
__global__ __launch_bounds__(512, 8) void mfma_proj5(
    const _Float16* __restrict__ X16, const _Float16* __restrict__ Wt5,
    const float* __restrict__ b0, void* __restrict__ C0,
    const float* __restrict__ b1, void* __restrict__ C1,
    const float* __restrict__ b2, void* __restrict__ C2,
    const float* __restrict__ b3, void* __restrict__ C3,
    const float* __restrict__ b4, void* __restrict__ C4)
{
    __shared__ _Float16 As[12288];
    __shared__ _Float16 Bs[12288];
    const int bid = (blockIdx.x & 7) * 104 + (blockIdx.x >> 3);
    int g, mblk, nblk;
    if (bid < 768) {
        g = bid >> 8; mblk = (bid & 255) >> 2; nblk = bid & 3;
    } else {
        const int t = bid - 768;
        g = 3 + (t >> 5); mblk = (t & 31) >> 2; nblk = t & 3;
    }
    const bool qry = g >= 3;
    const _Float16* A = X16 + (qry ? (size_t)8192 * 512 : 0);
    const _Float16* Wt = Wt5 + (size_t)g * 262144;
    const float* bias = (g == 0) ? b0 : (g == 1) ? b1 : (g == 2) ? b2
                      : (g == 3) ? b3 : b4;
    void* Cv = (g == 0) ? C0 : (g == 1) ? C1 : (g == 2) ? C2
             : (g == 3) ? C3 : C4;
    const int m0 = mblk * 128, n0 = nblk * 128;

    f32x4 acc[4][2];
#pragma unroll
    for (int mt = 0; mt < 4; ++mt)
#pragma unroll
        for (int nt = 0; nt < 2; ++nt) acc[mt][nt] = (f32x4)0.f;
    gemm8_f16<16>(A + (size_t)m0 * 512, Wt + (size_t)n0 * 512, As, Bs, acc);
    proj_epilogue8(acc, bias, Cv, m0, n0, 1);
}

// ---------------------------------------------------------------------------
// Output projection (A = cv16 fp16, M=1024, fp32 out). Grid: (8, 4).
// ---------------------------------------------------------------------------
__global__ __launch_bounds__(512, 4) void mfma_proj_out(
    const _Float16* __restrict__ A16, const _Float16* __restrict__ Wt,
    const float* __restrict__ bias, float* __restrict__ C)
{
    __shared__ _Float16 As[12288];
    __shared__ _Float16 Bs[12288];
    const int m0 = blockIdx.x * 128, n0 = blockIdx.y * 128;
    f32x4 acc[4][2];
#pragma unroll
    for (int mt = 0; mt < 4; ++mt)
#pragma unroll
        for (int nt = 0; nt < 2; ++nt) acc[mt][nt] = (f32x4)0.f;
    gemm8_f16<16>(A16 + (size_t)m0 * 512, Wt + (size_t)n0 * 512, As, Bs, acc);
    proj_epilogue8(acc, bias, C, m0, n0, 0);
}

// ---------------------------------------------------------------------------
// Energy (z-split): z<8 mono (b=z, +r, fp32 e_mono); z>=8 chunk (fp16
// e_chunk16). 512 blocks of 512 threads. mask read as int8.
// Grid: (kt=8, h=4, z=16).
// ---------------------------------------------------------------------------
__global__ __launch_bounds__(512, 4) void energy_mfma(
    const _Float16* __restrict__ Qm, const _Float16* __restrict__ Km,
    const _Float16* __restrict__ Qc, const _Float16* __restrict__ Kc,
    const signed char* __restrict__ mask8, float* __restrict__ e_mono,
    _Float16* __restrict__ e_chunk16, const float* __restrict__ r_ptr)
{
    __shared__ _Float16 As[12288];
    __shared__ _Float16 Bs[12288];
    const int tid = threadIdx.x;
    const int lane = tid & 63, wave = tid >> 6;
    const int wm = wave >> 2, wn = wave & 3;
    const int col = lane & 15, quad = lane >> 4;
    const int kt0 = blockIdx.x * 128;
    const int h = blockIdx.y;
    const int z = blockIdx.z;
    const int b = z & 7;
    const bool mono = z < 8;
    const _Float16* Qp = mono ? Qm : Qc;
    const _Float16* Kp = mono ? Km : Kc;
    const float rv = mono ? r_ptr[0] : 0.f;

    f32x4 acc[4][2];
#pragma unroll
    for (int mt = 0; mt < 4; ++mt)
#pragma unroll
        for (int nt = 0; nt < 2; ++nt) acc[mt][nt] = (f32x4)0.f;
    gemm8_f16<4>(Qp + (size_t)(b * 128) * 512 + h * 128,
                 Kp + (size_t)(b * 1024 + kt0) * 512 + h * 128, As, Bs, acc);

#pragma unroll
    for (int mt = 0; mt < 4; ++mt) {
        const int qb = wm * 64 + mt * 16 + quad * 4;
#pragma unroll
        for (int nt = 0; nt < 2; ++nt) {
            const int kc = kt0 + wn * 32 + nt * 16 + col;
#pragma unroll
            for (int r = 0; r < 4; ++r) {
                const int q = qb + r;
                const int mv = mask8[((size_t)b * 128 + q) * 1024 + kc];
                const size_t oi = (((size_t)b * 4 + h) * 128 + q) * 1024 + kc;
                float v = acc[mt][nt][r] * INV_SCALE + rv;
                if (mono) e_mono[oi] = mv ? v : NEG_INF;
                else      e_chunk16[oi] = (_Float16)(mv ? v : NEG_INF);
            }
        }
    }
}

// ---------------------------------------------------------------------------
// transcend_row: (pcp, invcp) for one (b,h,q) row computed by one wave.
// Fast transcendentals (__expf/__logf/v_rcp).
// ---------------------------------------------------------------------------
__device__ __forceinline__ void transcend_row(
    const float* __restrict__ Erow, int lane, float o_pcp[16], float o_inv[16])
{
    const float* E = Erow + lane * 16;
    float e[16];
    *(float4*)&e[0]  = *(const float4*)(E);
    *(float4*)&e[4]  = *(const float4*)(E + 4);
    *(float4*)&e[8]  = *(const float4*)(E + 8);
    *(float4*)&e[12] = *(const float4*)(E + 12);

    float p[16], l[16];
#pragma unroll
    for (int i = 0; i < 16; ++i) {
        p[i] = frcp(1.f + __expf(-e[i]));
        l[i] = __logf(fmaxf(1.f - p[i], EPS_MOCHA));
    }
    float incl[16];
    incl[0] = l[0];
#pragma unroll
    for (int i = 1; i < 16; ++i) incl[i] = incl[i - 1] + l[i];
    float total = incl[15];
    float x = wave_incl_scan(total);
    float base = x - total;  // exclusive across lanes
#pragma unroll
    for (int i = 0; i < 16; ++i) {
        float cl = base + (i ? incl[i - 1] : 0.f);
        float cp = __expf(cl);
        o_pcp[i] = p[i] * cp;
        o_inv[i] = frcp(fmaxf(cp, EPS_MOCHA));
    }
}

// ---------------------------------------------------------------------------
// alpha_pre: block = 8 consecutive rows (one wave each, same (b,h) panel);
// pcp shared wave->wave via LDS. Only wave 0 recomputes the previous row.
// G_q = pcp_{q-1} * invcp_q. Grid: 512 x 512.
// ---------------------------------------------------------------------------
#define SW2(k) ((k) + ((k) >> 4))

__global__ __launch_bounds__(512) void alpha_pre(
    const float* __restrict__ e_mono, float* __restrict__ G,
    float* __restrict__ pcp)
{
    __shared__ float pshare[8][1088];
    const int tid = threadIdx.x;
    const int lane = tid & 63;
    const int wid = tid >> 6;
    const int row = blockIdx.x * 8 + wid;
    const int q = row & 127;

    float pq[16], iq[16];
    transcend_row(e_mono + (size_t)row * 1024, lane, pq, iq);

    float* P = pcp + (size_t)row * 1024 + lane * 16;
    *(float4*)(P)      = *(float4*)&pq[0];
    *(float4*)(P + 4)  = *(float4*)&pq[4];
    *(float4*)(P + 8)  = *(float4*)&pq[8];
    *(float4*)(P + 12) = *(float4*)&pq[12];

#pragma unroll
    for (int i = 0; i < 16; ++i)
        pshare[wid][SW2(lane * 16 + i)] = pq[i];
    __syncthreads();

    float g[16];
    if (q == 0) {  // only wid==0 on panel boundary
#pragma unroll
        for (int i = 0; i < 16; ++i) g[i] = 0.f;
        if (lane == 0) g[0] = iq[0];
    } else if (wid > 0) {
#pragma unroll
        for (int i = 0; i < 16; ++i)
            g[i] = pshare[wid - 1][SW2(lane * 16 + i)] * iq[i];
    } else {
        float pm[16], im[16];
        transcend_row(e_mono + (size_t)(row - 1) * 1024, lane, pm, im);
#pragma unroll
        for (int i = 0; i < 16; ++i) g[i] = pm[i] * iq[i];
    }
    float* Gp = G + (size_t)row * 1024 + lane * 16;
    *(float4*)(Gp)      = *(float4*)&g[0];
    *(float4*)(Gp + 4)  = *(float4*)&g[4];
    *(float4*)(Gp + 8)  = *(float4*)&g[8];
    *(float4*)(Gp + 12) = *(float4*)&g[12];
}

// ---------------------------------------------------------------------------
// alpha_scan: one 256-thread block per (b,h); 4 k/lane; named prefetch
// registers g0..g3 / p0..p3 (no scratch), q-loop unrolled by 4. Reads G and
// pcp (pcp only used at the store, fully prefetched); writes alpha = pcp*S.
// Double-buffered cross-wave carry + one lgkmcnt-only barrier per step.
// ---------------------------------------------------------------------------
__global__ __launch_bounds__(256) void alpha_scan(
    const float* __restrict__ G, const float* __restrict__ pcp,
    float* __restrict__ alpha)
{
    __shared__ float carry[2][4];
    const int tid = threadIdx.x;
    const int lane = tid & 63, wid = tid >> 6;
    const int bh = blockIdx.x;
    const float* Gp = G + (size_t)bh * 131072 + tid * 4;
    const float* Pp = pcp + (size_t)bh * 131072 + tid * 4;
    float* Ap = alpha + (size_t)bh * 131072 + tid * 4;

    float4 g0 = *(const float4*)(Gp);
    float4 g1 = *(const float4*)(Gp + 1024);
    float4 g2 = *(const float4*)(Gp + 2048);
    float4 g3 = *(const float4*)(Gp + 3072);
    float4 p0 = *(const float4*)(Pp);
    float4 p1 = *(const float4*)(Pp + 1024);
    float4 p2 = *(const float4*)(Pp + 2048);
    float4 p3 = *(const float4*)(Pp + 3072);

    float Sv0 = 1.f, Sv1 = 1.f, Sv2 = 1.f, Sv3 = 1.f;  // S_{-1} = ones

#define SCAN_STEP(GV, PV, QQ)                                                \
    {                                                                        \
        float i0 = GV.x * Sv0;                                               \
        float i1 = fmaf(GV.y, Sv1, i0);                                      \
        float i2 = fmaf(GV.z, Sv2, i1);                                      \
        float i3 = fmaf(GV.w, Sv3, i2);                                      \
        float x = wave_incl_scan(i3);                                        \
        float base = x - i3;                                                 \
        if (lane == 63) carry[(QQ) & 1][wid] = x;                            \
        BARLG();                                                             \
        float pre = 0.f;                                                     \
        if (wid > 0) pre += carry[(QQ) & 1][0];                              \
        if (wid > 1) pre += carry[(QQ) & 1][1];                              \
        if (wid > 2) pre += carry[(QQ) & 1][2];                              \
        float ba = pre + base;                                               \
        Sv0 = ba + i0; Sv1 = ba + i1; Sv2 = ba + i2; Sv3 = ba + i3;          \
        float4 av = {PV.x * Sv0, PV.y * Sv1, PV.z * Sv2, PV.w * Sv3};        \
        *(float4*)(Ap + (size_t)(QQ) * 1024) = av;                           \
    }

    for (int q = 0; q < 128; q += 4) {
        SCAN_STEP(g0, p0, q);
        if (q + 4 < 128) {
            g0 = *(const float4*)(Gp + (size_t)(q + 4) * 1024);
            p0 = *(const float4*)(Pp + (size_t)(q + 4) * 1024);
        }
        SCAN_STEP(g1, p1, q + 1);
        if (q + 5 < 128) {
            g1 = *(const float4*)(Gp + (size_t)(q + 5) * 1024);
            p1 = *(const float4*)(Pp + (size_t)(q + 5) * 1024);
        }
        SCAN_STEP(g2, p2, q + 2);
        if (q + 6 < 128) {
            g2 = *(const float4*)(Gp + (size_t)(q + 6) * 1024);
            p2 = *(const float4*)(Pp + (size_t)(q + 6) * 1024);
        }
        SCAN_STEP(g3, p3, q + 3);
        if (q + 7 < 128) {
            g3 = *(const float4*)(Gp + (size_t)(q + 7) * 1024);
            p3 = *(const float4*)(Pp + (size_t)(q + 7) * 1024);
        }
    }
#undef SCAN_STEP
}

// ---------------------------------------------------------------------------
// Beta: reads alpha (single 16MB array); moving sums via shfl; fast exp/rcp.
// Grid: (q=128, b=8).
// ---------------------------------------------------------------------------
__global__ __launch_bounds__(256) void beta_kernel(
    const _Float16* __restrict__ e_chunk16, const float* __restrict__ alpha,
    _Float16* __restrict__ beta)
{
    __shared__ float red[4];
    __shared__ float edge_sx[4][4];    // lane63's sx per wave
    __shared__ float edge_t[4][4][4];  // lane0's t per wave per hm
    const int q = blockIdx.x, b = blockIdx.y;
    const int tid = threadIdx.x;
    const int lane = tid & 63, wid = tid >> 6;
    const int k4 = tid * 4;

    float av[4][4];
#pragma unroll
    for (int hm = 0; hm < 4; ++hm) {
        const size_t off = (((size_t)b * 4 + hm) * 128 + q) * 1024 + k4;
        float4 a = *(const float4*)(alpha + off);
        av[hm][0] = a.x; av[hm][1] = a.y; av[hm][2] = a.z; av[hm][3] = a.w;
    }

    for (int hc = 0; hc < 4; ++hc) {
        half4v ev = *(const half4v*)(e_chunk16 + (((size_t)b * 4 + hc) * 128 + q) * 1024 + k4);
        float e[4] = {(float)ev[0], (float)ev[1], (float)ev[2], (float)ev[3]};

        float mx = fmaxf(fmaxf(e[0], e[1]), fmaxf(e[2], e[3]));
#pragma unroll
        for (int off = 32; off >= 1; off >>= 1)
            mx = fmaxf(mx, __shfl_xor(mx, off, 64));
        if (lane == 0) red[wid] = mx;
        __syncthreads();  // bar1: red ready (also fences edge reuse)
        mx = fmaxf(fmaxf(red[0], red[1]), fmaxf(red[2], red[3]));

        float sx[4];
#pragma unroll
        for (int i = 0; i < 4; ++i)
            sx[i] = fmaxf(__expf(e[i] - mx), 1e-5f);
        if (lane == 63) {
            edge_sx[wid][0] = sx[0]; edge_sx[wid][1] = sx[1];
            edge_sx[wid][2] = sx[2]; edge_sx[wid][3] = sx[3];
        }
        __syncthreads();  // bar2: edge_sx ready

        float p1 = __shfl_up(sx[3], 1, 64);
        float p2 = __shfl_up(sx[2], 1, 64);
        float p3 = __shfl_up(sx[1], 1, 64);
        if (lane == 0) {
            if (wid > 0) {
                p1 = edge_sx[wid - 1][3];
                p2 = edge_sx[wid - 1][2];
                p3 = edge_sx[wid - 1][1];
            } else {
                p1 = 0.f; p2 = 0.f; p3 = 0.f;
            }
        }
        float den[4];
        den[0] = sx[0] + p1 + p2 + p3;
        den[1] = sx[1] + sx[0] + p1 + p2;
        den[2] = sx[2] + sx[1] + sx[0] + p1;
        den[3] = sx[3] + sx[2] + sx[1] + sx[0];
        float rd[4];
#pragma unroll
        for (int i = 0; i < 4; ++i) rd[i] = frcp(den[i]);

        float t[4][4];
#pragma unroll
        for (int hm = 0; hm < 4; ++hm)
#pragma unroll
            for (int i = 0; i < 4; ++i)
                t[hm][i] = av[hm][i] * rd[i];
        if (lane == 0) {
#pragma unroll
            for (int hm = 0; hm < 4; ++hm) {
                edge_t[wid][hm][0] = t[hm][0]; edge_t[wid][hm][1] = t[hm][1];
                edge_t[wid][hm][2] = t[hm][2]; edge_t[wid][hm][3] = t[hm][3];
            }
        }
        __syncthreads();  // bar3: edge_t ready

#pragma unroll
        for (int hm = 0; hm < 4; ++hm) {
            float n1 = __shfl_down(t[hm][0], 1, 64);
            float n2 = __shfl_down(t[hm][1], 1, 64);
            float n3 = __shfl_down(t[hm][2], 1, 64);
            if (lane == 63) {
                if (wid < 3) {
                    n1 = edge_t[wid + 1][hm][0];
                    n2 = edge_t[wid + 1][hm][1];
                    n3 = edge_t[wid + 1][hm][2];
                } else {
                    n1 = 0.f; n2 = 0.f; n3 = 0.f;
                }
            }
            float o0 = sx[0] * (t[hm][0] + t[hm][1] + t[hm][2] + t[hm][3]);
            float o1 = sx[1] * (t[hm][1] + t[hm][2] + t[hm][3] + n1);
            float o2 = sx[2] * (t[hm][2] + t[hm][3] + n1 + n2);
            float o3 = sx[3] * (t[hm][3] + n1 + n2 + n3);
            _Float16* Brow = beta + (((size_t)b * 16 + hm * 4 + hc) * 128 + q) * 1024;
            half4v hv = {(_Float16)o0, (_Float16)o1, (_Float16)o2, (_Float16)o3};
            *(half4v*)(Brow + k4) = hv;
        }
    }
}

// ---------------------------------------------------------------------------
// Context via MFMA: per block (qh,h,b) compute cv16[b, q0..q0+63, h*32..+32]
// = beta16[b,h,q,:] @ V16[b,:,h*32..]. M=64, N=32, K=1024, BK=64, 16 steps.
// 256 threads (4 waves, 2m x 2n, wave tile 32x16, acc[2][1]). Reg-staged
// PADDED LDS (stride 72 halfs; gll can't pad), double buffer, one BARLG per
// step (global loads for step+1 stay in flight across it; the counted vmcnt
// wait happens at the reg->LDS write after MFMA). Grid: (2, 16, 8).
// ---------------------------------------------------------------------------
__global__ __launch_bounds__(256) void context_mfma(
    const _Float16* __restrict__ beta, const _Float16* __restrict__ V16,
    _Float16* __restrict__ cv16)
{
    __shared__ _Float16 As[2][64][72];   // [buf][q][k]  (pad 8)
    __shared__ _Float16 Bs[2][32][72];   // [buf][d][k]  (pad 8)
    const int qh = blockIdx.x, h = blockIdx.y, b = blockIdx.z;
    const int tid = threadIdx.x;
    const int lane = tid & 63, wave = tid >> 6;
    const int wm = wave >> 1, wn = wave & 1;
    const int col = lane & 15, quad = lane >> 4;
    const int q0 = qh * 64;

    // A staging map: thread t -> row r=t>>2 (0..63), seg cs=t&3 (16 k each)
    const int ar = tid >> 2, acs = tid & 3;
    const _Float16* Ag = beta + (((size_t)b * 16 + h) * 128 + q0 + ar) * 1024 + acs * 16;
    // B staging map: thread t -> k kk=t>>2 (0..63), d seg ds=t&3 (8 d each)
    const int bk = tid >> 2, bds = tid & 3;
    const _Float16* Vg = V16 + ((size_t)b * 1024 + bk) * 512 + h * 32 + bds * 8;

    f32x4 acc[2];
    acc[0] = (f32x4)0.f; acc[1] = (f32x4)0.f;

    // prologue: load step 0 regs, write buf0
    half8 ra0 = *(const half8*)(Ag);
    half8 ra1 = *(const half8*)(Ag + 8);
    half8 rv  = *(const half8*)(Vg);
    *(half8*)&As[0][ar][acs * 16]     = ra0;
    *(half8*)&As[0][ar][acs * 16 + 8] = ra1;
#pragma unroll
    for (int j = 0; j < 8; ++j) Bs[0][bds * 8 + j][bk] = rv[j];
    BARLG();

    for (int ks = 0; ks < 16; ++ks) {
        const int cur = ks & 1, nxt = cur ^ 1;
        // issue step ks+1 global loads early (land under MFMA below)
        if (ks + 1 < 16) {
            const int k0 = (ks + 1) * 64;
            ra0 = *(const half8*)(Ag + k0);
            ra1 = *(const half8*)(Ag + k0 + 8);
            rv  = *(const half8*)(Vg + (size_t)k0 * 512);
        }
        // compute current tile: 2 k-subtiles of 32
#pragma unroll
        for (int sub = 0; sub < 2; ++sub) {
            half8 bf = *(const half8*)&Bs[cur][wn * 16 + col][sub * 32 + quad * 8];
#pragma unroll
            for (int mt = 0; mt < 2; ++mt) {
                half8 af = *(const half8*)&As[cur][wm * 32 + mt * 16 + col][sub * 32 + quad * 8];
                acc[mt] = __builtin_amdgcn_mfma_f32_16x16x32_f16(af, bf, acc[mt], 0, 0, 0);
            }
        }
        // write step ks+1 regs into the other buffer (implicit counted vmcnt)
        if (ks + 1 < 16) {
            *(half8*)&As[nxt][ar][acs * 16]     = ra0;
            *(half8*)&As[nxt][ar][acs * 16 + 8] = ra1;
#pragma unroll
            for (int j = 0; j < 8; ++j) Bs[nxt][bds * 8 + j][bk] = rv[j];
        }
        BARLG();
    }

    // epilogue: q = q0 + wm*32 + mt*16 + quad*4 + r; d = h*32 + wn*16 + col
#pragma unroll
    for (int mt = 0; mt < 2; ++mt) {
        const int qb = q0 + wm * 32 + mt * 16 + quad * 4;
#pragma unroll
        for (int r = 0; r < 4; ++r) {
            _Float16* Cp = cv16 + ((size_t)b * 128 + qb + r) * 512 + h * 32 + wn * 16 + col;
            *Cp = (_Float16)acc[mt][r];
        }
    }
}

// ---------------------------------------------------------------------------
extern "C" void kernel_launch(void* const* d_in, const int* in_sizes, int n_in,
                              void* d_out, int out_size, void* d_ws, size_t ws_size,
                              hipStream_t stream)
{
    const float* key_x   = (const float*)d_in[0];
    const float* query_x = (const float*)d_in[1];
    const int*   mask    = (const int*)d_in[2];
    const float* wk_m = (const float*)d_in[3];
    const float* bk_m = (const float*)d_in[4];
    const float* wq_m = (const float*)d_in[5];
    const float* bq_m = (const float*)d_in[6];
    const float* r    = (const float*)d_in[7];
    const float* wk_c = (const float*)d_in[8];
    const float* bk_c = (const float*)d_in[9];
    const float* wq_c = (const float*)d_in[10];
    const float* bq_c = (const float*)d_in[11];
    const float* wv   = (const float*)d_in[12];
    const float* bv   = (const float*)d_in[13];
    const float* wo   = (const float*)d_in[14];
    const float* bo   = (const float*)d_in[15];
    float* out = (float*)d_out;

    float* ws = (float*)d_ws;
    _Float16* hws = (_Float16*)d_ws;
    const size_t MEGF = 1024 * 1024;
    // Float-unit layout (fp16 offsets are 2x float offsets), lifetime-audited:
    //  phase A (prep_all, proj5, energy):
    //    Km16 f[0,2), Kc16 f[2,4), Qm16 f[4,4.25), Qc16 f[4.25,4.5),
    //    X16 f[8,10.25) [dead after proj5], mask8 f[10.25,10.5),
    //    e_mono f[11,15), e_chunk16 f[17,19), V16 f[19,21),
    //    Wt5 f[27,27.625), Wt_wo f[27.625,27.75) [live to proj_out]
    //  phase B (alpha): G f[0,4), pcp f[4,8), alpha f[23,27)
    //  phase C (beta/context): beta16 f[8,16) (X16+mask8+e_mono dead;
    //    alpha live), cv16 f[27.75,28). Peak 28 MEGF.
    _Float16* Km16  = hws;                          // f 0
    _Float16* Kc16  = hws + 4 * MEGF;               // f 2
    _Float16* Qm16  = hws + 8 * MEGF;               // f 4
    _Float16* Qc16  = hws + 8 * MEGF + 524288;      // f 4.25
    _Float16* X16   = hws + 16 * MEGF;              // f 8, 2.25 MEGF
    signed char* mask8 = (signed char*)(hws + 20 * MEGF + MEGF / 2);  // f 10.25
    float* e_mono  = ws + 11 * MEGF;
    _Float16* e_chunk16 = hws + 34 * MEGF;          // f 17
    _Float16* V16  = hws + 38 * MEGF;               // f 19, 2 MEGF
    float* G       = ws;                            // f 0
    float* pcp     = ws + 4 * MEGF;                 // f 4
    float* alpha   = ws + 23 * MEGF;                // f 23
    _Float16* beta16 = hws + 16 * MEGF;             // f 8 (phase C)
    _Float16* Wt5   = hws + 54 * MEGF;              // f 27
    _Float16* Wt_wo = hws + 54 * MEGF + 5 * 262144; // f 27.625
    _Float16* cv16  = hws + 55 * MEGF + MEGF / 2;   // f 27.75

    // 0) weight packing + activation cvt + mask->int8 in one launch
    prep_all<<<dim3(3200), 256, 0, stream>>>(
        wk_m, wk_c, wv, wq_m, wq_c, wo, key_x, query_x, mask,
        Wt5, Wt_wo, X16, mask8);
    // 1) all five projections (832-block grid, 512 threads, XCD swizzle)
    mfma_proj5<<<dim3(832), 512, 0, stream>>>(
        X16, Wt5, bk_m, Km16, bk_c, Kc16, bv, V16, bq_m, Qm16, bq_c, Qc16);
    // 2) both energies, z-split
    energy_mfma<<<dim3(8, 4, 16), 512, 0, stream>>>(
        Qm16, Km16, Qc16, Kc16, mask8, e_mono, e_chunk16, r);
    // 3) monotonic alpha: G/pcp precompute + k-parallel scan -> alpha=pcp*S
    alpha_pre<<<dim3(512), 512, 0, stream>>>(e_mono, G, pcp);
    alpha_scan<<<dim3(32), 256, 0, stream>>>(G, pcp, alpha);
    // 4) chunkwise beta (reads alpha only)
    beta_kernel<<<dim3(128, 8), 256, 0, stream>>>(e_chunk16, alpha, beta16);
    // 5) context vectors -> cv16 (MFMA)
    context_mfma<<<dim3(2, 16, 8), 256, 0, stream>>>(beta16, V16, cv16);
    // 6) output projection
    mfma_proj_out<<<dim3(8, 4), 512, 0, stream>>>(cv16, Wt_wo, bo, out);
}